// Round 1
// baseline (34.950 us; speedup 1.0000x reference)
//
#include <hip/hip_runtime.h>
#include <math.h>

#define NBOX 8732
#define NCONF 21
#define NB 2
#define MAXV 2048
#define CONF_TH 0.5f
#define IOU_TH 0.5f
#define ENT_STRIDE 28   // floats per candidate entry: idx, score, box4, conf21, pad

__device__ __constant__ int c_off[7] = {0, 5776, 7942, 8542, 8692, 8728, 8732};
__device__ __constant__ int c_H[6]   = {38, 19, 10, 5, 3, 1};
__device__ __constant__ int c_A[6]   = {4, 6, 6, 6, 4, 4};

// anchor (h, w) per level k, anchor a — matches numpy double-math then f32 cast
__device__ inline void anchor_hw(int k, int a, float& h, float& w) {
    const double SC[7] = {0.1, 0.2, 0.375, 0.55, 0.725, 0.9, 1.075};
    int nar = (k >= 1 && k <= 3) ? 5 : 3;
    double s = SC[k], sn = SC[k + 1];
    if (a < nar) {
        double ar;
        switch (a) {
            case 0: ar = 1.0;    break;
            case 1: ar = 2.0;    break;
            case 2: ar = 0.5;    break;
            case 3: ar = 3.0;    break;
            default: ar = 0.3333; break;
        }
        double r = sqrt(ar);
        h = (float)(s / r);
        w = (float)(s * r);
    } else {
        float sp = (float)sqrt(s * sn);
        h = sp; w = sp;
    }
}

__global__ __launch_bounds__(256)
void decode_kernel(const float* __restrict__ f0, const float* __restrict__ f1,
                   const float* __restrict__ f2, const float* __restrict__ f3,
                   const float* __restrict__ f4, const float* __restrict__ f5,
                   unsigned int* __restrict__ counters,
                   float* __restrict__ entries) {
    int t = blockIdx.x * blockDim.x + threadIdx.x;
    if (t >= NB * NBOX) return;
    int b = t / NBOX;
    int n = t % NBOX;

    // level lookup
    int k = 0;
    while (n >= c_off[k + 1]) ++k;
    int local = n - c_off[k];
    int A = c_A[k], H = c_H[k];
    int a = local % A;
    int cell = local / A;
    int x = cell % H;   // cx index (second spatial axis)
    int y = cell / H;   // cy index (first spatial axis)

    const float* f;
    switch (k) {
        case 0: f = f0; break; case 1: f = f1; break; case 2: f = f2; break;
        case 3: f = f3; break; case 4: f = f4; break; default: f = f5; break;
    }
    const float* p = f + ((((size_t)b * H + y) * H + x) * (size_t)A + a) * (4 + NCONF);

    float t0 = p[0], t1 = p[1], t2 = p[2], t3 = p[3];

    float lg[NCONF];
    float m = -1e30f;
#pragma unroll
    for (int c = 0; c < NCONF; c++) { lg[c] = p[4 + c]; m = fmaxf(m, lg[c]); }
    float sum = 0.f;
#pragma unroll
    for (int c = 0; c < NCONF; c++) { lg[c] = expf(lg[c] - m); sum += lg[c]; }
    float conf[NCONF];
#pragma unroll
    for (int c = 0; c < NCONF; c++) conf[c] = lg[c] / sum;
    float score = 0.f;
#pragma unroll
    for (int c = 0; c < NCONF - 1; c++) score = fmaxf(score, conf[c]);

    if (score >= CONF_TH) {
        float ah, aw;
        anchor_hw(k, a, ah, aw);
        float acx = ((float)x + 0.5f) / (float)H;
        float acy = ((float)y + 0.5f) / (float)H;
        float cx = acx + aw * t0;
        float cy = acy + ah * t1;
        float hh = ah * expf(t2);
        float ww = aw * expf(t3);

        unsigned int pos = atomicAdd(&counters[b], 1u);
        if (pos < MAXV) {
            float* e = entries + ((size_t)b * MAXV + pos) * ENT_STRIDE;
            e[0] = (float)n;   // original index (exact in f32, n < 2^24)
            e[1] = score;
            e[2] = cx; e[3] = cy; e[4] = hh; e[5] = ww;
#pragma unroll
            for (int c = 0; c < NCONF; c++) e[6 + c] = conf[c];
        }
    }
}

__global__ __launch_bounds__(256)
void nms_kernel(const unsigned int* __restrict__ counters,
                const float* __restrict__ entries,
                float* __restrict__ out) {
    int b = blockIdx.x;
    __shared__ float s_sc[MAXV];
    __shared__ int   s_id[MAXV];
    __shared__ float s_bx[MAXV][4];
    __shared__ short s_ord[MAXV];

    int K = (int)counters[b];
    if (K > MAXV) K = MAXV;

    for (int j = threadIdx.x; j < K; j += blockDim.x) {
        const float* e = entries + ((size_t)b * MAXV + j) * ENT_STRIDE;
        s_id[j] = (int)e[0];
        s_sc[j] = e[1];
        s_bx[j][0] = e[2]; s_bx[j][1] = e[3];
        s_bx[j][2] = e[4]; s_bx[j][3] = e[5];
    }
    __syncthreads();

    // stable rank: score desc, tie -> original index asc (matches stable argsort(-s))
    for (int j = threadIdx.x; j < K; j += blockDim.x) {
        float sj = s_sc[j];
        int   ij = s_id[j];
        int rank = 0;
        for (int i = 0; i < K; i++) {
            float si = s_sc[i];
            if (si > sj || (si == sj && s_id[i] < ij)) rank++;
        }
        s_ord[rank] = (short)j;
    }
    __syncthreads();

    // suppression: box at rank r is suppressed iff IoU with ANY earlier-ranked
    // valid box >= 0.5 (reference conditions on valid, not keep)
    for (int r = threadIdx.x; r < K; r += blockDim.x) {
        int j = s_ord[r];
        float cx = s_bx[j][0], cy = s_bx[j][1], hh = s_bx[j][2], ww = s_bx[j][3];
        float ax1 = cx - ww * 0.5f, ay1 = cy - hh * 0.5f;
        float ax2 = cx + ww * 0.5f, ay2 = cy + hh * 0.5f;
        float areaA = (ax2 - ax1) * (ay2 - ay1);
        bool sup = false;
        for (int q = 0; q < r && !sup; q++) {
            int i = s_ord[q];
            float icx = s_bx[i][0], icy = s_bx[i][1], ihh = s_bx[i][2], iww = s_bx[i][3];
            float bx1 = icx - iww * 0.5f, by1 = icy - ihh * 0.5f;
            float bx2 = icx + iww * 0.5f, by2 = icy + ihh * 0.5f;
            float lx = fmaxf(ax1, bx1), ly = fmaxf(ay1, by1);
            float rx = fminf(ax2, bx2), ry = fminf(ay2, by2);
            float iw = fmaxf(rx - lx, 0.f), ih = fmaxf(ry - ly, 0.f);
            float inter = iw * ih;
            float areaB = (bx2 - bx1) * (by2 - by1);
            float iou = inter / (areaA + areaB - inter + 1e-8f);
            if (iou >= IOU_TH) sup = true;
        }
        if (!sup) {
            float* o = out + ((size_t)b * NBOX + r) * (4 + NCONF);
            o[0] = cx; o[1] = cy; o[2] = hh; o[3] = ww;
            const float* e = entries + ((size_t)b * MAXV + j) * ENT_STRIDE;
#pragma unroll
            for (int c = 0; c < NCONF; c++) o[4 + c] = e[6 + c];
        }
    }
}

extern "C" void kernel_launch(void* const* d_in, const int* in_sizes, int n_in,
                              void* d_out, int out_size, void* d_ws, size_t ws_size,
                              hipStream_t stream) {
    const float* f0 = (const float*)d_in[0];
    const float* f1 = (const float*)d_in[1];
    const float* f2 = (const float*)d_in[2];
    const float* f3 = (const float*)d_in[3];
    const float* f4 = (const float*)d_in[4];
    const float* f5 = (const float*)d_in[5];

    unsigned int* counters = (unsigned int*)d_ws;
    float* entries = (float*)((char*)d_ws + 256);

    // zero counters + output every call (deterministic under graph replay)
    hipMemsetAsync(d_ws, 0, 256, stream);
    hipMemsetAsync(d_out, 0, (size_t)out_size * sizeof(float), stream);

    int total = NB * NBOX;
    int blocks = (total + 255) / 256;
    decode_kernel<<<blocks, 256, 0, stream>>>(f0, f1, f2, f3, f4, f5, counters, entries);
    nms_kernel<<<NB, 256, 0, stream>>>(counters, entries, (float*)d_out);
}